// Round 1
// baseline (68.588 us; speedup 1.0000x reference)
//
#include <hip/hip_runtime.h>

// FEM stiffness matrix assembly (negated) on a triangulated mesh.
// out = -M, M[a,b] = sum over triangles t containing nodes a,b of
//   (grad phi_a . grad phi_b) * area(t)
//
// For triangle (p0,p1,p2) with A = [[1,x0,y0],[1,x1,y1],[1,x2,y2]]:
//   det = (x1-x0)(y2-y0) - (x2-x0)(y1-y0)   (= 2 * signed area)
//   grad phi_0 = ((y1-y2)/det, (x2-x1)/det)
//   grad phi_1 = ((y2-y0)/det, (x0-x2)/det)
//   grad phi_2 = ((y0-y1)/det, (x1-x0)/det)
//   area = 0.5*|det|
// Matches the reference's jnp.linalg.solve(A, I) slopes[1:,:] columns.

__global__ void fem_assemble_kernel(const float* __restrict__ pts,
                                    const int* __restrict__ cmap,
                                    float* __restrict__ out,
                                    int T, int N) {
    int t = blockIdx.x * blockDim.x + threadIdx.x;
    if (t >= T) return;

    int ni = cmap[3 * t + 0];
    int nj = cmap[3 * t + 1];
    int nk = cmap[3 * t + 2];

    float x0 = pts[2 * ni + 0], y0 = pts[2 * ni + 1];
    float x1 = pts[2 * nj + 0], y1 = pts[2 * nj + 1];
    float x2 = pts[2 * nk + 0], y2 = pts[2 * nk + 1];

    float det = (x1 - x0) * (y2 - y0) - (x2 - x0) * (y1 - y0);
    float area = 0.5f * fabsf(det);
    float inv = 1.0f / det;

    float gix = (y1 - y2) * inv, giy = (x2 - x1) * inv;
    float gjx = (y2 - y0) * inv, gjy = (x0 - x2) * inv;
    float gkx = (y0 - y1) * inv, gky = (x1 - x0) * inv;

    float Mii = (gix * gix + giy * giy) * area;
    float Mjj = (gjx * gjx + gjy * gjy) * area;
    float Mkk = (gkx * gkx + gky * gky) * area;
    float Mij = (gix * gjx + giy * gjy) * area;
    float Mjk = (gjx * gkx + gjy * gky) * area;
    float Mki = (gkx * gix + gky * giy) * area;

    size_t Ns = (size_t)N;
    // Diagonal
    atomicAdd(&out[(size_t)ni * Ns + ni], -Mii);
    atomicAdd(&out[(size_t)nj * Ns + nj], -Mjj);
    atomicAdd(&out[(size_t)nk * Ns + nk], -Mkk);
    // Off-diagonal (symmetric: both (a,b) and (b,a))
    atomicAdd(&out[(size_t)ni * Ns + nj], -Mij);
    atomicAdd(&out[(size_t)nj * Ns + ni], -Mij);
    atomicAdd(&out[(size_t)nj * Ns + nk], -Mjk);
    atomicAdd(&out[(size_t)nk * Ns + nj], -Mjk);
    atomicAdd(&out[(size_t)nk * Ns + ni], -Mki);
    atomicAdd(&out[(size_t)ni * Ns + nk], -Mki);
}

extern "C" void kernel_launch(void* const* d_in, const int* in_sizes, int n_in,
                              void* d_out, int out_size, void* d_ws, size_t ws_size,
                              hipStream_t stream) {
    const float* pts = (const float*)d_in[0];   // (N, 2) float32
    const int* cmap = (const int*)d_in[1];      // (T, 3) int
    // d_in[2] = num_meshpoints scalar (device); derive sizes host-side instead.

    int N = in_sizes[0] / 2;   // number of mesh nodes (9216)
    int T = in_sizes[1] / 3;   // number of triangles (18050)

    float* out = (float*)d_out;

    // Zero the dense output every call (harness poisons once, atomics would
    // otherwise accumulate across graph replays).
    hipMemsetAsync(d_out, 0, (size_t)out_size * sizeof(float), stream);

    int block = 256;
    int grid = (T + block - 1) / block;
    fem_assemble_kernel<<<grid, block, 0, stream>>>(pts, cmap, out, T, N);
}